// Round 8
// baseline (1108.949 us; speedup 1.0000x reference)
//
#include <hip/hip_runtime.h>

// ---------------------------------------------------------------------------
// Decoder: fused cvt -> fused h0/c0 init GEMM -> gx GEMM -> ONE persistent
// kernel (regular launch, 256 blocks = 1/CU) for all 32 LSTM steps WITH the
// FC (out = sigmoid(h @ W_fc^T + b_fc)) folded into the per-step idle time.
// Protocol = round-5 exact (proven 176us): sparse one-flag-per-64B-line,
// h-store -> vmcnt ack -> barrier -> tid0 flag store -> wave-0 poll ->
// release barrier. Round-7 regressions (dense flags = LLC line contention,
// per-wave poll = 8x traffic) reverted. New: waves 1-6 compute this block's
// 40-vocab-col FC slab for time-row t-1 (input h_t, confirmed complete by
// the previous bottom poll) while wave 0 polls; tail row 31 after a final
// poll. Poll widened to full-grid (4 sparse lines/lane) since FC needs both
// batch halves. The 80us standalone FC GEMM is deleted.
// ---------------------------------------------------------------------------

#define B_  64
#define T_  32
#define E_  512
#define H_  1024
#define V_  10000
#define F_  2048

typedef short short8 __attribute__((ext_vector_type(8)));
typedef float floatx4 __attribute__((ext_vector_type(4)));

__device__ __forceinline__ float bf2f(unsigned short u) {
  union { unsigned int i; float f; } c; c.i = ((unsigned int)u) << 16; return c.f;
}
__device__ __forceinline__ unsigned short f2bf(float f) {
  union { float f; unsigned int i; } c; c.f = f;
  unsigned int x = c.i;
  return (unsigned short)((x + 0x7fffu + ((x >> 16) & 1u)) >> 16);
}
__device__ __forceinline__ float sigmoidf_(float x) {
  return 1.0f / (1.0f + __expf(-x));
}
// async global->LDS, 16B per lane. LDS dest = wave-uniform base + lane*16.
__device__ __forceinline__ void gl_lds16(const unsigned short* g, unsigned short* l) {
  __builtin_amdgcn_global_load_lds(
      (const __attribute__((address_space(1))) unsigned int*)g,
      (__attribute__((address_space(3))) unsigned int*)l, 16, 0, 0);
}
// bijective XCD-chunked block remap (m204 formula; identity when nwg < 8)
__device__ __forceinline__ int xcd_swz(int lin, int nwg) {
  if (nwg < 8) return lin;
  int q = nwg >> 3, r = nwg & 7;
  int xcd = lin & 7, pos = lin >> 3;
  return (xcd < r ? xcd * (q + 1) : r * (q + 1) + (xcd - r) * q) + pos;
}

// ---------------- fused fp32 -> bf16 convert for all 6 arrays --------------
#define C_WIH  524288    // 4H*E/4
#define C_WHH  1048576   // 4H*H/4
#define C_WFC  2560000   // V*H/4
#define C_WI0  524288    // H*F/4
#define C_WC0  524288
#define C_FEA  32768     // B*F/4
#define C_TOT  (C_WIH + C_WHH + C_WFC + C_WI0 + C_WC0 + C_FEA)
#define NFLAGW 4096      // 256 flags x 16 dwords (one 64B line each; SPARSE)

__global__ __launch_bounds__(256) void cvt_all(
    const float* __restrict__ s0, const float* __restrict__ s1,
    const float* __restrict__ s2, const float* __restrict__ s3,
    const float* __restrict__ s4, const float* __restrict__ s5,
    unsigned short* __restrict__ d0, unsigned short* __restrict__ d1,
    unsigned short* __restrict__ d2, unsigned short* __restrict__ d3,
    unsigned short* __restrict__ d4, unsigned short* __restrict__ d5,
    unsigned int* __restrict__ flags) {
  // reset the persistent-kernel arrival flags (visible at coherent point via
  // end-of-dispatch release -- proven path, rounds 4-5)
  if (blockIdx.x == 0) {
    for (int w = threadIdx.x; w < NFLAGW; w += 256) flags[w] = 0u;
  }
  int i = blockIdx.x * blockDim.x + threadIdx.x;
  int stride = gridDim.x * blockDim.x;
  for (; i < C_TOT; i += stride) {
    const float* s; unsigned short* d; int j = i;
    if (j < C_WIH)            { s = s0; d = d0; }
    else if ((j -= C_WIH) < C_WHH) { s = s1; d = d1; }
    else if ((j -= C_WHH) < C_WFC) { s = s2; d = d2; }
    else if ((j -= C_WFC) < C_WI0) { s = s3; d = d3; }
    else if ((j -= C_WI0) < C_WC0) { s = s4; d = d4; }
    else { j -= C_WC0; s = s5; d = d5; }
    float4 v = ((const float4*)s)[j];
    ushort4 o;
    o.x = f2bf(v.x); o.y = f2bf(v.y); o.z = f2bf(v.z); o.w = f2bf(v.w);
    ((ushort4*)d)[j] = o;
  }
}

// ---------------- embedding gather -> bf16, rows ordered (t*64+b) ----------
__global__ __launch_bounds__(128) void embed_gather(
    const float* __restrict__ table, const int* __restrict__ captions,
    unsigned short* __restrict__ out) {
  int row = blockIdx.x;            // row = t*B + b
  int t = row >> 6, b = row & 63;
  int idx = captions[b * T_ + t];
  const float4* src = (const float4*)(table + (size_t)idx * E_);
  ushort4* dst = (ushort4*)(out + (size_t)row * E_);
  for (int e = threadIdx.x; e < E_ / 4; e += blockDim.x) {
    float4 v = src[e];
    ushort4 o;
    o.x = f2bf(v.x); o.y = f2bf(v.y); o.z = f2bf(v.z); o.w = f2bf(v.w);
    dst[e] = o;
  }
}

// ---------------- 128x128 LDS-staged bf16 MFMA GEMM ------------------------
// C = act(A @ W^T + bias).  2-phase double-buffer, XOR bank swizzle,
// bijective XCD swizzle. OUT_INIT: N=2048 fused h0|c0 split epilogue.
template <int ACT_SIGMOID, int OUT_BF16, int OUT_INIT>
__global__ __launch_bounds__(256) void mfma_gemm128(
    const unsigned short* __restrict__ A, const unsigned short* __restrict__ W,
    const float* __restrict__ bias1, const float* __restrict__ bias2,
    void* __restrict__ out, void* __restrict__ out2, int M, int N, int K) {
  __shared__ unsigned short At[2][128 * 32];   // 16 KB
  __shared__ unsigned short Wt[2][128 * 32];   // 16 KB

  const int tid  = threadIdx.x;
  const int lane = tid & 63;
  const int wave = tid >> 6;
  const int l15  = lane & 15;
  const int quad = lane >> 4;
  const int wm   = (wave >> 1) * 64;
  const int wn   = (wave & 1) * 64;

  const int gx  = gridDim.x;
  const int nwg = gx * gridDim.y;
  const int wg  = xcd_swz(blockIdx.y * gx + blockIdx.x, nwg);
  const int m0  = (wg % gx) * 128;
  const int n0  = (wg / gx) * 128;
  const int ksl = (quad ^ (l15 & 3)) * 8;  // swizzled k-chunk for frag reads

  const int c0i = tid, c1i = tid + 256;
  const int ar0 = c0i >> 2, ak0 = (((c0i & 3) ^ (ar0 & 3)) * 8);
  const int ar1 = c1i >> 2, ak1 = (((c1i & 3) ^ (ar1 & 3)) * 8);
  int am0 = m0 + ar0; if (am0 > M - 1) am0 = M - 1;
  int am1 = m0 + ar1; if (am1 > M - 1) am1 = M - 1;
  int wn0 = n0 + ar0; if (wn0 > N - 1) wn0 = N - 1;
  int wn1 = n0 + ar1; if (wn1 > N - 1) wn1 = N - 1;
  const unsigned short* Ag0 = A + (size_t)am0 * K + ak0;
  const unsigned short* Ag1 = A + (size_t)am1 * K + ak1;
  const unsigned short* Wg0 = W + (size_t)wn0 * K + ak0;
  const unsigned short* Wg1 = W + (size_t)wn1 * K + ak1;

  floatx4 acc[4][4];
#pragma unroll
  for (int i = 0; i < 4; ++i)
#pragma unroll
    for (int j = 0; j < 4; ++j) acc[i][j] = (floatx4){0.f, 0.f, 0.f, 0.f};

  // prologue stage of k-tile 0 into buffer 0
  gl_lds16(Ag0, &At[0][c0i * 8]);
  gl_lds16(Ag1, &At[0][c1i * 8]);
  gl_lds16(Wg0, &Wt[0][c0i * 8]);
  gl_lds16(Wg1, &Wt[0][c1i * 8]);
  __syncthreads();

  int cur = 0;
  for (int k0 = 0; k0 < K; k0 += 32) {
    const int kn = k0 + 32;
    if (kn < K) {                      // issue next tile before compute
      const int nb = cur ^ 1;
      gl_lds16(Ag0 + kn, &At[nb][c0i * 8]);
      gl_lds16(Ag1 + kn, &At[nb][c1i * 8]);
      gl_lds16(Wg0 + kn, &Wt[nb][c0i * 8]);
      gl_lds16(Wg1 + kn, &Wt[nb][c1i * 8]);
    }
    short8 a[4], b[4];
#pragma unroll
    for (int mt = 0; mt < 4; ++mt)
      a[mt] = *(const short8*)&At[cur][(wm + mt * 16 + l15) * 32 + ksl];
#pragma unroll
    for (int nt = 0; nt < 4; ++nt)
      b[nt] = *(const short8*)&Wt[cur][(wn + nt * 16 + l15) * 32 + ksl];
#pragma unroll
    for (int mt = 0; mt < 4; ++mt)
#pragma unroll
      for (int nt = 0; nt < 4; ++nt)
        acc[mt][nt] = __builtin_amdgcn_mfma_f32_16x16x32_bf16(a[mt], b[nt], acc[mt][nt], 0, 0, 0);
    __syncthreads();                   // drains vmcnt: next tile resident
    cur ^= 1;
  }

#pragma unroll
  for (int nt = 0; nt < 4; ++nt) {
    int col = n0 + wn + nt * 16 + l15;
    if (col >= N) continue;
    float bsum;
    if (OUT_INIT)
      bsum = (col < H_) ? bias1[col] : bias2[col - H_];
    else
      bsum = (bias1 ? bias1[col] : 0.f) + (bias2 ? bias2[col] : 0.f);
#pragma unroll
    for (int mt = 0; mt < 4; ++mt) {
#pragma unroll
      for (int r = 0; r < 4; ++r) {
        int m = m0 + wm + mt * 16 + quad * 4 + r;
        if (m >= M) continue;
        float v = acc[mt][nt][r] + bsum;
        if (ACT_SIGMOID) v = sigmoidf_(v);
        if (OUT_INIT) {
          if (col < H_)
            ((unsigned short*)out)[(size_t)m * H_ + col] = f2bf(v);
          else
            ((float*)out2)[(size_t)m * H_ + (col - H_)] = v;
        } else if (OUT_BF16) {
          ((unsigned short*)out)[(size_t)m * N + col] = f2bf(v);
        } else {
          ((float*)out)[(size_t)m * N + col] = v;
        }
      }
    }
  }
}

// ---------------- in-kernel FC slab (runs in the step idle window) ---------
// Block covers vocab cols [vb, vb+40). 12 tiles = 4 batch-frags x 3 col-frags
// (48 cols, last 8 masked). Waves 1..6 take 2 tiles each. Operands read with
// NORMAL loads (h slab is LLC-complete and first-touched after the poll;
// W_fc slab is per-XCD L2-resident, 96KB/block).
__device__ __forceinline__ void fc_slab(
    const unsigned short* __restrict__ hsrc,   // [64,H] bf16, complete
    const unsigned short* __restrict__ W_fc_b, // [V,H] bf16
    const float* __restrict__ b_fc,            // [V]
    float* __restrict__ orow,                  // out + row_t*B*V
    int vb, int wave, int l15, int quad) {
  const int t0 = (wave - 1) * 2, t1 = t0 + 1;
  const int bf0 = t0 / 3, cf0 = t0 % 3;
  const int bf1 = t1 / 3, cf1 = t1 % 3;
  const int kq8 = quad * 8;
  const int c0 = vb + cf0 * 16 + l15;
  const int c1 = vb + cf1 * 16 + l15;
  const int wr0 = c0 < V_ ? c0 : V_ - 1;
  const int wr1 = c1 < V_ ? c1 : V_ - 1;
  const unsigned short* a0p = hsrc + (size_t)(bf0 * 16 + l15) * H_ + kq8;
  const unsigned short* a1p = hsrc + (size_t)(bf1 * 16 + l15) * H_ + kq8;
  const unsigned short* b0p = W_fc_b + (size_t)wr0 * H_ + kq8;
  const unsigned short* b1p = W_fc_b + (size_t)wr1 * H_ + kq8;
  floatx4 acc0 = (floatx4){0.f, 0.f, 0.f, 0.f}, acc1 = acc0;
#pragma unroll 4
  for (int k = 0; k < H_; k += 32) {
    short8 a0 = *(const short8*)(a0p + k);
    short8 b0 = *(const short8*)(b0p + k);
    short8 a1 = *(const short8*)(a1p + k);
    short8 b1 = *(const short8*)(b1p + k);
    acc0 = __builtin_amdgcn_mfma_f32_16x16x32_bf16(a0, b0, acc0, 0, 0, 0);
    acc1 = __builtin_amdgcn_mfma_f32_16x16x32_bf16(a1, b1, acc1, 0, 0, 0);
  }
  if (c0 < vb + 40 && c0 < V_) {
    const float bs = b_fc[c0];
#pragma unroll
    for (int r = 0; r < 4; ++r)
      orow[(size_t)(bf0 * 16 + quad * 4 + r) * V_ + c0] = sigmoidf_(acc0[r] + bs);
  }
  if (c1 < vb + 40 && c1 < V_) {
    const float bs = b_fc[c1];
#pragma unroll
    for (int r = 0; r < 4; ++r)
      orow[(size_t)(bf1 * 16 + quad * 4 + r) * V_ + c1] = sigmoidf_(acc1[r] + bs);
  }
}

// ---------------- persistent 32-step LSTM + folded FC (256 blocks) ---------
// Block = (colgroup cg of 8 h-cols, batch-half bh of 32); 82,944B LDS ->
// exactly 1 block/CU. Round-5 protocol verbatim; poll widened to all 256
// flags (4 sparse lines/lane) because FC consumes both batch halves.
#define WSPAD2 1032   // 1024 + 8 bf16 pad per row (granule spread)
__global__ __launch_bounds__(512, 2) void lstm_persistent(
    const unsigned short* __restrict__ W_hh_b,  // [4H,H] bf16
    const unsigned short* __restrict__ gx_b,    // [T,B,4H] bf16
    const float* __restrict__ c0_f32,           // [B,H] f32 initial c
    unsigned short* __restrict__ h_all,         // [(T+1),B,H] bf16
    unsigned int* __restrict__ flags,           // 256 x 16-dword lines, =0
    const unsigned short* __restrict__ W_fc_b,  // [V,H] bf16
    const float* __restrict__ b_fc,             // [V]
    float* __restrict__ out) {                  // [T,B,V] f32
  __shared__ unsigned short Ws[32 * WSPAD2];    // ~64.5 KB
  __shared__ float gbuf[4][32][33];             // ~16.9 KB

  const int tid  = threadIdx.x;
  const int lane = tid & 63;
  const int wave = tid >> 6;        // 0..7
  const int l15  = lane & 15;
  const int quad = lane >> 4;
  const int kb   = quad * 8;
  const int bid  = blockIdx.x;
  const int cg   = bid >> 1;        // col-group: cols [cg*8, cg*8+8)
  const int bh   = bid & 1;         // batch half: batches [bh*32, bh*32+32)
  const int colbase = cg * 8;
  const int kq   = wave >> 1;       // K quarter: [kq*256, kq*256+256)
  const int mt   = wave & 1;        // batch frag: bh*32 + mt*16 .. +16
  const int vb   = bid * 40;        // FC vocab slab base (bids 250+ skip)

  // ---- one-time: stage 32 W_hh rows (gate-major n=g*8+j) as 64 1KB units --
#pragma unroll
  for (int it = 0; it < 8; ++it) {
    int u = wave * 8 + it;          // 0..63
    int n = u >> 1, half = u & 1;
    int grow = (n >> 3) * H_ + colbase + (n & 7);
    gl_lds16(W_hh_b + (size_t)grow * H_ + half * 512 + lane * 8,
             &Ws[n * WSPAD2 + half * 512]);
  }

  // ---- one-time: cell threads load initial c into registers ---------------
  const int bq = tid >> 2;          // 0..31 (batch in half), tid<128 only
  const int cp = tid & 3;           // col pair: cols 2cp, 2cp+1
  const int gb = bh * 32 + bq;
  float cA = 0.f, cB = 0.f;
  if (tid < 128) {
    float2 cv = *(const float2*)(c0_f32 + (size_t)gb * H_ + colbase + 2 * cp);
    cA = cv.x; cB = cv.y;
  }

  const unsigned short* hbase =
      h_all + (size_t)(bh * 32 + mt * 16 + l15) * H_ + kq * 256 + kb;
  const unsigned short* wb0 = &Ws[(size_t)(l15)      * WSPAD2 + kq * 256 + kb];
  const unsigned short* wb1 = &Ws[(size_t)(16 + l15) * WSPAD2 + kq * 256 + kb];
  // full-grid poll: lane l checks sparse flag lines l, l+64, l+128, l+192
  const unsigned int* pf0 = flags + (size_t)(lane)       * 16;
  const unsigned int* pf1 = flags + (size_t)(lane + 64)  * 16;
  const unsigned int* pf2 = flags + (size_t)(lane + 128) * 16;
  const unsigned int* pf3 = flags + (size_t)(lane + 192) * 16;

  __syncthreads();   // drains vmcnt: W staging complete

  for (int t = 0; t < T_; ++t) {
    // ---- gx for this step (precomputed; normal loads) ---------------------
    unsigned int ui = 0, uf = 0, ug = 0, uo = 0;
    if (tid < 128) {
      const unsigned short* gxp =
          gx_b + (size_t)t * (B_ * 4 * H_) + (size_t)gb * (4 * H_) + colbase + 2 * cp;
      ui = *(const unsigned int*)(gxp + 0 * H_);
      uf = *(const unsigned int*)(gxp + 1 * H_);
      ug = *(const unsigned int*)(gxp + 2 * H_);
      uo = *(const unsigned int*)(gxp + 3 * H_);
    }

    // ---- h_t read: sc0 sc1 bypasses (possibly stale) local L2/L1 ----------
    const unsigned short* hp = hbase + (size_t)t * (B_ * H_);
    short8 hx[8];
#pragma unroll
    for (int i = 0; i < 8; ++i)
      asm volatile("global_load_dwordx4 %0, %1, off sc0 sc1"
                   : "=v"(hx[i]) : "v"(hp + i * 32) : "memory");
    asm volatile("s_waitcnt vmcnt(0)" ::: "memory");
    __builtin_amdgcn_sched_barrier(0);   // rule#18: pin MFMA after the wait

    // ---- 16 MFMAs: 8 k-chunks x 2 row-frags -------------------------------
    floatx4 A0 = (floatx4){0.f, 0.f, 0.f, 0.f}, A1 = A0;
#pragma unroll
    for (int i = 0; i < 8; ++i) {
      short8 w0 = *(const short8*)(wb0 + i * 32);
      short8 w1 = *(const short8*)(wb1 + i * 32);
      A0 = __builtin_amdgcn_mfma_f32_16x16x32_bf16(hx[i], w0, A0, 0, 0, 0);
      A1 = __builtin_amdgcn_mfma_f32_16x16x32_bf16(hx[i], w1, A1, 0, 0, 0);
    }
#pragma unroll
    for (int r = 0; r < 4; ++r) {
      gbuf[kq][mt * 16 + quad * 4 + r][l15]      = A0[r];
      gbuf[kq][mt * 16 + quad * 4 + r][16 + l15] = A1[r];
    }
    __syncthreads();

    // ---- cell math: thread owns (batch gb, cols colbase+2cp, +1) ----------
    if (tid < 128) {
      const int c0c = 2 * cp, c1c = 2 * cp + 1;
      float giA = gbuf[0][bq][ 0 + c0c] + gbuf[1][bq][ 0 + c0c]
                + gbuf[2][bq][ 0 + c0c] + gbuf[3][bq][ 0 + c0c] + bf2f((unsigned short)(ui & 0xffff));
      float gfA = gbuf[0][bq][ 8 + c0c] + gbuf[1][bq][ 8 + c0c]
                + gbuf[2][bq][ 8 + c0c] + gbuf[3][bq][ 8 + c0c] + bf2f((unsigned short)(uf & 0xffff));
      float ggA = gbuf[0][bq][16 + c0c] + gbuf[1][bq][16 + c0c]
                + gbuf[2][bq][16 + c0c] + gbuf[3][bq][16 + c0c] + bf2f((unsigned short)(ug & 0xffff));
      float goA = gbuf[0][bq][24 + c0c] + gbuf[1][bq][24 + c0c]
                + gbuf[2][bq][24 + c0c] + gbuf[3][bq][24 + c0c] + bf2f((unsigned short)(uo & 0xffff));
      float giB = gbuf[0][bq][ 0 + c1c] + gbuf[1][bq][ 0 + c1c]
                + gbuf[2][bq][ 0 + c1c] + gbuf[3][bq][ 0 + c1c] + bf2f((unsigned short)(ui >> 16));
      float gfB = gbuf[0][bq][ 8 + c1c] + gbuf[1][bq][ 8 + c1c]
                + gbuf[2][bq][ 8 + c1c] + gbuf[3][bq][ 8 + c1c] + bf2f((unsigned short)(uf >> 16));
      float ggB = gbuf[0][bq][16 + c1c] + gbuf[1][bq][16 + c1c]
                + gbuf[2][bq][16 + c1c] + gbuf[3][bq][16 + c1c] + bf2f((unsigned short)(ug >> 16));
      float goB = gbuf[0][bq][24 + c1c] + gbuf[1][bq][24 + c1c]
                + gbuf[2][bq][24 + c1c] + gbuf[3][bq][24 + c1c] + bf2f((unsigned short)(uo >> 16));
      giA = sigmoidf_(giA); gfA = sigmoidf_(gfA); ggA = tanhf(ggA); goA = sigmoidf_(goA);
      giB = sigmoidf_(giB); gfB = sigmoidf_(gfB); ggB = tanhf(ggB); goB = sigmoidf_(goB);
      cA = gfA * cA + giA * ggA;
      cB = gfB * cB + giB * ggB;
      float hA = goA * tanhf(cA);
      float hB = goB * tanhf(cB);
      unsigned int hv = (unsigned int)f2bf(hA) | ((unsigned int)f2bf(hB) << 16);
      unsigned int* hop = (unsigned int*)(h_all + (size_t)(t + 1) * (B_ * H_)
                                          + (size_t)gb * H_ + colbase + 2 * cp);
      // write-through to coherent point so every XCD can read it next step
      asm volatile("global_store_dword %0, %1, off sc0 sc1"
                   :: "v"(hop), "v"(hv) : "memory");
      asm volatile("s_waitcnt vmcnt(0)" ::: "memory");   // ack at LLC
    }

    // ---- bottom: barrier -> flag publish -> {wave0 poll || waves1-6 FC} ---
    __syncthreads();                 // h stores acked; gbuf reads complete
    if (tid == 0) {
      const unsigned int tg = (unsigned int)(t + 1);
      unsigned int* myf = flags + (size_t)bid * 16;
      asm volatile("global_store_dword %0, %1, off sc0 sc1"
                   :: "v"(myf), "v"(tg) : "memory");
    }
    if (t > 0 && wave >= 1 && wave <= 6 && vb < V_)
      fc_slab(h_all + (size_t)t * (B_ * H_), W_fc_b, b_fc,
              out + (size_t)(t - 1) * (B_ * V_), vb, wave, l15, quad);
    if (t < T_ - 1 && wave == 0) {
      const unsigned int tgt = (unsigned int)(t + 1);
      for (;;) {
        unsigned int v0, v1, v2, v3;
        asm volatile("global_load_dword %0, %1, off sc0 sc1"
                     : "=v"(v0) : "v"(pf0) : "memory");
        asm volatile("global_load_dword %0, %1, off sc0 sc1"
                     : "=v"(v1) : "v"(pf1) : "memory");
        asm volatile("global_load_dword %0, %1, off sc0 sc1"
                     : "=v"(v2) : "v"(pf2) : "memory");
        asm volatile("global_load_dword %0, %1, off sc0 sc1"
                     : "=v"(v3) : "v"(pf3) : "memory");
        asm volatile("s_waitcnt vmcnt(0)" ::: "memory");
        if (__all(v0 >= tgt && v1 >= tgt && v2 >= tgt && v3 >= tgt)) break;
        __builtin_amdgcn_s_sleep(1);
      }
    }
    __syncthreads();                 // release all waves into step t+1
  }

  // ---- tail: confirm h_T complete, then FC time-row T-1 -------------------
  if (wave == 0) {
    const unsigned int tgt = (unsigned int)T_;
    for (;;) {
      unsigned int v0, v1, v2, v3;
      asm volatile("global_load_dword %0, %1, off sc0 sc1"
                   : "=v"(v0) : "v"(pf0) : "memory");
      asm volatile("global_load_dword %0, %1, off sc0 sc1"
                   : "=v"(v1) : "v"(pf1) : "memory");
      asm volatile("global_load_dword %0, %1, off sc0 sc1"
                   : "=v"(v2) : "v"(pf2) : "memory");
      asm volatile("global_load_dword %0, %1, off sc0 sc1"
                   : "=v"(v3) : "v"(pf3) : "memory");
      asm volatile("s_waitcnt vmcnt(0)" ::: "memory");
      if (__all(v0 >= tgt && v1 >= tgt && v2 >= tgt && v3 >= tgt)) break;
      __builtin_amdgcn_s_sleep(1);
    }
  }
  __syncthreads();
  if (wave >= 1 && wave <= 6 && vb < V_)
    fc_slab(h_all + (size_t)T_ * (B_ * H_), W_fc_b, b_fc,
            out + (size_t)(T_ - 1) * (B_ * V_), vb, wave, l15, quad);
}

// ---------------------------------------------------------------------------
extern "C" void kernel_launch(void* const* d_in, const int* in_sizes, int n_in,
                              void* d_out, int out_size, void* d_ws, size_t ws_size,
                              hipStream_t stream) {
  const float* features    = (const float*)d_in[0];
  const int*   captions    = (const int*)d_in[1];
  const float* embed_table = (const float*)d_in[2];
  const float* W_init_h    = (const float*)d_in[3];
  const float* b_init_h    = (const float*)d_in[4];
  const float* W_init_c    = (const float*)d_in[5];
  const float* b_init_c    = (const float*)d_in[6];
  const float* W_ih        = (const float*)d_in[7];
  const float* b_ih        = (const float*)d_in[8];
  const float* W_hh        = (const float*)d_in[9];
  const float* b_hh        = (const float*)d_in[10];
  const float* W_fc        = (const float*)d_in[11];
  const float* b_fc        = (const float*)d_in[12];
  float* out = (float*)d_out;

  // ---- workspace carve-up (bump allocator, 256B aligned) ----
  char* ws = (char*)d_ws;
  auto alloc = [&](size_t bytes) -> char* {
    char* p = ws;
    ws += (bytes + 255) & ~(size_t)255;
    return p;
  };
  unsigned short* W_ih_b  = (unsigned short*)alloc((size_t)4 * H_ * E_ * 2);
  unsigned short* W_hh_b  = (unsigned short*)alloc((size_t)4 * H_ * H_ * 2);
  unsigned short* W_fc_b  = (unsigned short*)alloc((size_t)V_ * H_ * 2);
  // NOTE: Wih0_b and Wic0_b must stay CONTIGUOUS (fused [2H,F] init GEMM).
  unsigned short* Wih0_b  = (unsigned short*)alloc((size_t)H_ * F_ * 2);
  unsigned short* Wic0_b  = (unsigned short*)alloc((size_t)H_ * F_ * 2);
  unsigned short* feat_b  = (unsigned short*)alloc((size_t)B_ * F_ * 2);
  unsigned short* emb_b   = (unsigned short*)alloc((size_t)T_ * B_ * E_ * 2);
  unsigned short* gx_b    = (unsigned short*)alloc((size_t)T_ * B_ * 4 * H_ * 2);
  unsigned short* h_all   = (unsigned short*)alloc((size_t)(T_ + 1) * B_ * H_ * 2);
  float*          c_f32   = (float*)alloc((size_t)B_ * H_ * 4);
  unsigned int*   flags   = (unsigned int*)alloc((size_t)NFLAGW * 4);
  (void)ws_size; (void)in_sizes; (void)n_in; (void)out_size; (void)Wic0_b;

  // ---- one fused fp32->bf16 conversion + flag reset ----
  hipLaunchKernelGGL(cvt_all, dim3(4096), dim3(256), 0, stream,
                     W_ih, W_hh, W_fc, W_init_h, W_init_c, features,
                     W_ih_b, W_hh_b, W_fc_b, Wih0_b, Wic0_b, feat_b, flags);

  hipLaunchKernelGGL(embed_gather, dim3(T_ * B_), dim3(128), 0, stream,
                     embed_table, captions, emb_b);

  // ---- fused h0|c0 init: one GEMM over N=2048 (Wih0_b||Wic0_b contiguous) -
  hipLaunchKernelGGL((mfma_gemm128<0, 1, 1>), dim3(1, 2 * H_ / 128), dim3(256), 0, stream,
                     feat_b, Wih0_b, b_init_h, b_init_c,
                     (void*)h_all, (void*)c_f32, B_, 2 * H_, F_);

  // ---- gx = emb @ W_ih^T + b_ih + b_hh for all t ----
  hipLaunchKernelGGL((mfma_gemm128<0, 1, 0>), dim3(T_ * B_ / 128, 4 * H_ / 128), dim3(256), 0, stream,
                     emb_b, W_ih_b, b_ih, b_hh, (void*)gx_b, (void*)nullptr,
                     T_ * B_, 4 * H_, E_);

  // ---- all 32 recurrent steps + the ENTIRE FC in ONE persistent kernel ----
  hipLaunchKernelGGL(lstm_persistent, dim3(2 * H_ / 8), dim3(512), 0, stream,
                     W_hh_b, gx_b, c_f32, h_all, flags, W_fc_b, b_fc, out);
}

// Round 9
// 511.617 us; speedup vs baseline: 2.1675x; 2.1675x over previous
//
#include <hip/hip_runtime.h>

// ---------------------------------------------------------------------------
// Decoder: fused cvt -> fused h0/c0 init GEMM -> gx GEMM -> ONE persistent
// role-split kernel: 128 STEP blocks (r5 protocol verbatim) + 128 FC blocks
// (W_fc slab LDS-resident, computes out[t-1] in the step-latency shadow).
// FC-fold history: r1 failed (blocks>CUs serialize), r2 failed (VGPR cap in
// step path), r8 failed (FETCH 50->218MB: W_fc evicted from L2 every step).
// This design: 128+128 = 256 = CU count (1 block/CU by LDS); FC state is in
// DEDICATED blocks (no step-path VGPR cost); W_fc staged to LDS ONCE (158KB
// of 160KB/CU -- possible only because of the role split). FC blocks only
// READ step flags -- no new sync edges, steps never wait on FC.
// ---------------------------------------------------------------------------

#define B_  64
#define T_  32
#define E_  512
#define H_  1024
#define V_  10000
#define F_  2048

typedef short short8 __attribute__((ext_vector_type(8)));
typedef float floatx4 __attribute__((ext_vector_type(4)));

__device__ __forceinline__ float bf2f(unsigned short u) {
  union { unsigned int i; float f; } c; c.i = ((unsigned int)u) << 16; return c.f;
}
__device__ __forceinline__ unsigned short f2bf(float f) {
  union { float f; unsigned int i; } c; c.f = f;
  unsigned int x = c.i;
  return (unsigned short)((x + 0x7fffu + ((x >> 16) & 1u)) >> 16);
}
__device__ __forceinline__ float sigmoidf_(float x) {
  return 1.0f / (1.0f + __expf(-x));
}
// async global->LDS, 16B per lane. LDS dest = wave-uniform base + lane*16.
__device__ __forceinline__ void gl_lds16(const unsigned short* g, unsigned short* l) {
  __builtin_amdgcn_global_load_lds(
      (const __attribute__((address_space(1))) unsigned int*)g,
      (__attribute__((address_space(3))) unsigned int*)l, 16, 0, 0);
}
// bijective XCD-chunked block remap (m204 formula; identity when nwg < 8)
__device__ __forceinline__ int xcd_swz(int lin, int nwg) {
  if (nwg < 8) return lin;
  int q = nwg >> 3, r = nwg & 7;
  int xcd = lin & 7, pos = lin >> 3;
  return (xcd < r ? xcd * (q + 1) : r * (q + 1) + (xcd - r) * q) + pos;
}

// ---------------- fused fp32 -> bf16 convert for all 6 arrays --------------
#define C_WIH  524288    // 4H*E/4
#define C_WHH  1048576   // 4H*H/4
#define C_WFC  2560000   // V*H/4
#define C_WI0  524288    // H*F/4
#define C_WC0  524288
#define C_FEA  32768     // B*F/4
#define C_TOT  (C_WIH + C_WHH + C_WFC + C_WI0 + C_WC0 + C_FEA)
#define NFLAGW 4096      // 256 flags x 16 dwords (one 64B line each; SPARSE)

__global__ __launch_bounds__(256) void cvt_all(
    const float* __restrict__ s0, const float* __restrict__ s1,
    const float* __restrict__ s2, const float* __restrict__ s3,
    const float* __restrict__ s4, const float* __restrict__ s5,
    unsigned short* __restrict__ d0, unsigned short* __restrict__ d1,
    unsigned short* __restrict__ d2, unsigned short* __restrict__ d3,
    unsigned short* __restrict__ d4, unsigned short* __restrict__ d5,
    unsigned int* __restrict__ flags) {
  // reset the persistent-kernel arrival flags (visible at coherent point via
  // end-of-dispatch release -- proven path, rounds 4-5)
  if (blockIdx.x == 0) {
    for (int w = threadIdx.x; w < NFLAGW; w += 256) flags[w] = 0u;
  }
  int i = blockIdx.x * blockDim.x + threadIdx.x;
  int stride = gridDim.x * blockDim.x;
  for (; i < C_TOT; i += stride) {
    const float* s; unsigned short* d; int j = i;
    if (j < C_WIH)            { s = s0; d = d0; }
    else if ((j -= C_WIH) < C_WHH) { s = s1; d = d1; }
    else if ((j -= C_WHH) < C_WFC) { s = s2; d = d2; }
    else if ((j -= C_WFC) < C_WI0) { s = s3; d = d3; }
    else if ((j -= C_WI0) < C_WC0) { s = s4; d = d4; }
    else { j -= C_WC0; s = s5; d = d5; }
    float4 v = ((const float4*)s)[j];
    ushort4 o;
    o.x = f2bf(v.x); o.y = f2bf(v.y); o.z = f2bf(v.z); o.w = f2bf(v.w);
    ((ushort4*)d)[j] = o;
  }
}

// ---------------- embedding gather -> bf16, rows ordered (t*64+b) ----------
__global__ __launch_bounds__(128) void embed_gather(
    const float* __restrict__ table, const int* __restrict__ captions,
    unsigned short* __restrict__ out) {
  int row = blockIdx.x;            // row = t*B + b
  int t = row >> 6, b = row & 63;
  int idx = captions[b * T_ + t];
  const float4* src = (const float4*)(table + (size_t)idx * E_);
  ushort4* dst = (ushort4*)(out + (size_t)row * E_);
  for (int e = threadIdx.x; e < E_ / 4; e += blockDim.x) {
    float4 v = src[e];
    ushort4 o;
    o.x = f2bf(v.x); o.y = f2bf(v.y); o.z = f2bf(v.z); o.w = f2bf(v.w);
    dst[e] = o;
  }
}

// ---------------- 128x128 LDS-staged bf16 MFMA GEMM ------------------------
// C = act(A @ W^T + bias).  2-phase double-buffer, XOR bank swizzle,
// bijective XCD swizzle. OUT_INIT: N=2048 fused h0|c0 split epilogue.
template <int ACT_SIGMOID, int OUT_BF16, int OUT_INIT>
__global__ __launch_bounds__(256) void mfma_gemm128(
    const unsigned short* __restrict__ A, const unsigned short* __restrict__ W,
    const float* __restrict__ bias1, const float* __restrict__ bias2,
    void* __restrict__ out, void* __restrict__ out2, int M, int N, int K) {
  __shared__ unsigned short At[2][128 * 32];   // 16 KB
  __shared__ unsigned short Wt[2][128 * 32];   // 16 KB

  const int tid  = threadIdx.x;
  const int lane = tid & 63;
  const int wave = tid >> 6;
  const int l15  = lane & 15;
  const int quad = lane >> 4;
  const int wm   = (wave >> 1) * 64;
  const int wn   = (wave & 1) * 64;

  const int gx  = gridDim.x;
  const int nwg = gx * gridDim.y;
  const int wg  = xcd_swz(blockIdx.y * gx + blockIdx.x, nwg);
  const int m0  = (wg % gx) * 128;
  const int n0  = (wg / gx) * 128;
  const int ksl = (quad ^ (l15 & 3)) * 8;  // swizzled k-chunk for frag reads

  const int c0i = tid, c1i = tid + 256;
  const int ar0 = c0i >> 2, ak0 = (((c0i & 3) ^ (ar0 & 3)) * 8);
  const int ar1 = c1i >> 2, ak1 = (((c1i & 3) ^ (ar1 & 3)) * 8);
  int am0 = m0 + ar0; if (am0 > M - 1) am0 = M - 1;
  int am1 = m0 + ar1; if (am1 > M - 1) am1 = M - 1;
  int wn0 = n0 + ar0; if (wn0 > N - 1) wn0 = N - 1;
  int wn1 = n0 + ar1; if (wn1 > N - 1) wn1 = N - 1;
  const unsigned short* Ag0 = A + (size_t)am0 * K + ak0;
  const unsigned short* Ag1 = A + (size_t)am1 * K + ak1;
  const unsigned short* Wg0 = W + (size_t)wn0 * K + ak0;
  const unsigned short* Wg1 = W + (size_t)wn1 * K + ak1;

  floatx4 acc[4][4];
#pragma unroll
  for (int i = 0; i < 4; ++i)
#pragma unroll
    for (int j = 0; j < 4; ++j) acc[i][j] = (floatx4){0.f, 0.f, 0.f, 0.f};

  gl_lds16(Ag0, &At[0][c0i * 8]);
  gl_lds16(Ag1, &At[0][c1i * 8]);
  gl_lds16(Wg0, &Wt[0][c0i * 8]);
  gl_lds16(Wg1, &Wt[0][c1i * 8]);
  __syncthreads();

  int cur = 0;
  for (int k0 = 0; k0 < K; k0 += 32) {
    const int kn = k0 + 32;
    if (kn < K) {
      const int nb = cur ^ 1;
      gl_lds16(Ag0 + kn, &At[nb][c0i * 8]);
      gl_lds16(Ag1 + kn, &At[nb][c1i * 8]);
      gl_lds16(Wg0 + kn, &Wt[nb][c0i * 8]);
      gl_lds16(Wg1 + kn, &Wt[nb][c1i * 8]);
    }
    short8 a[4], b[4];
#pragma unroll
    for (int mt = 0; mt < 4; ++mt)
      a[mt] = *(const short8*)&At[cur][(wm + mt * 16 + l15) * 32 + ksl];
#pragma unroll
    for (int nt = 0; nt < 4; ++nt)
      b[nt] = *(const short8*)&Wt[cur][(wn + nt * 16 + l15) * 32 + ksl];
#pragma unroll
    for (int mt = 0; mt < 4; ++mt)
#pragma unroll
      for (int nt = 0; nt < 4; ++nt)
        acc[mt][nt] = __builtin_amdgcn_mfma_f32_16x16x32_bf16(a[mt], b[nt], acc[mt][nt], 0, 0, 0);
    __syncthreads();
    cur ^= 1;
  }

#pragma unroll
  for (int nt = 0; nt < 4; ++nt) {
    int col = n0 + wn + nt * 16 + l15;
    if (col >= N) continue;
    float bsum;
    if (OUT_INIT)
      bsum = (col < H_) ? bias1[col] : bias2[col - H_];
    else
      bsum = (bias1 ? bias1[col] : 0.f) + (bias2 ? bias2[col] : 0.f);
#pragma unroll
    for (int mt = 0; mt < 4; ++mt) {
#pragma unroll
      for (int r = 0; r < 4; ++r) {
        int m = m0 + wm + mt * 16 + quad * 4 + r;
        if (m >= M) continue;
        float v = acc[mt][nt][r] + bsum;
        if (ACT_SIGMOID) v = sigmoidf_(v);
        if (OUT_INIT) {
          if (col < H_)
            ((unsigned short*)out)[(size_t)m * H_ + col] = f2bf(v);
          else
            ((float*)out2)[(size_t)m * H_ + (col - H_)] = v;
        } else if (OUT_BF16) {
          ((unsigned short*)out)[(size_t)m * N + col] = f2bf(v);
        } else {
          ((float*)out)[(size_t)m * N + col] = v;
        }
      }
    }
  }
}

// ---------------- persistent role-split kernel (256 blocks x 512 thr) ------
// STEP blocks (0..127): 8 h-cols x full batch; r5 flag protocol verbatim.
//   LDS overlay: Ws 32x1032 shorts (66,048B) + gbuf[4][64][33] f32 (33,792B).
// FC blocks (128..255): 79-vocab-row W_fc slab XOR-swizzle-staged to LDS
//   (161,792B) once; per step: wave0 polls step flags >= t, waves 1..4
//   compute batch-frag (w-1) x 5 col-frags of out[t-1] from h_all[t]
//   (a-frag loaded once per k-chunk, reused x5).
#define WSPAD2 1032
#define SMEMB  161792   // = 79 * 2048; >= step overlay (99,840)
__global__ __launch_bounds__(512, 2) void lstm_fused(
    const unsigned short* __restrict__ W_hh_b,  // [4H,H] bf16
    const unsigned short* __restrict__ gx_b,    // [T,B,4H] bf16
    const float* __restrict__ c0_f32,           // [B,H] f32 initial c
    unsigned short* __restrict__ h_all,         // [(T+1),B,H] bf16
    unsigned int* __restrict__ flags,           // 256 x 16-dword lines, =0
    const unsigned short* __restrict__ W_fc_b,  // [V,H] bf16
    const float* __restrict__ b_fc,             // [V]
    float* __restrict__ out) {                  // [T,B,V] f32
  __shared__ __align__(16) unsigned char smem[SMEMB];

  const int tid  = threadIdx.x;
  const int lane = tid & 63;
  const int wave = tid >> 6;        // 0..7
  const int l15  = lane & 15;
  const int quad = lane >> 4;
  const int bid  = blockIdx.x;
  // poll targets shared by both roles: step flags are bids 0..127;
  // lane l checks sparse lines l and l+64.
  const unsigned int* pf0 = flags + (size_t)(lane)      * 16;
  const unsigned int* pf1 = flags + (size_t)(lane + 64) * 16;

  if (bid < 128) {
    // ======================= STEP role =======================
    unsigned short* Ws = (unsigned short*)smem;
    float (*gbuf)[64][33] = (float (*)[64][33])(smem + 66048);
    const int colbase = bid * 8;      // cols [colbase, colbase+8)
    const int kb  = quad * 8;
    const int kq  = wave >> 1;        // K quarter
    const int bf0 = (wave & 1) * 2;   // batch frags bf0, bf0+1
    const int bf1 = bf0 + 1;

    // one-time: stage 32 W_hh rows (gate-major n=g*8+j) as 64 1KB half-rows
#pragma unroll
    for (int it = 0; it < 8; ++it) {
      int u = wave * 8 + it;          // 0..63
      int n = u >> 1, half = u & 1;
      int grow = (n >> 3) * H_ + colbase + (n & 7);
      gl_lds16(W_hh_b + (size_t)grow * H_ + half * 512 + lane * 8,
               &Ws[n * WSPAD2 + half * 512]);
    }

    // one-time: cell threads (tid<256) load initial c
    const int cb = tid >> 2;          // batch 0..63
    const int cp = tid & 3;           // col pair
    float cA = 0.f, cB = 0.f;
    if (tid < 256) {
      float2 cv = *(const float2*)(c0_f32 + (size_t)cb * H_ + colbase + 2 * cp);
      cA = cv.x; cB = cv.y;
    }

    const unsigned short* hb0 = h_all + (size_t)(bf0 * 16 + l15) * H_ + kq * 256 + kb;
    const unsigned short* hb1 = h_all + (size_t)(bf1 * 16 + l15) * H_ + kq * 256 + kb;
    const unsigned short* wb0 = &Ws[(size_t)(l15)      * WSPAD2 + kq * 256 + kb];
    const unsigned short* wb1 = &Ws[(size_t)(16 + l15) * WSPAD2 + kq * 256 + kb];

    __syncthreads();   // W staging complete

    for (int t = 0; t < T_; ++t) {
      // gx for this step (precomputed; normal loads)
      unsigned int ui = 0, uf = 0, ug = 0, uo = 0;
      if (tid < 256) {
        const unsigned short* gxp =
            gx_b + (size_t)t * (B_ * 4 * H_) + (size_t)cb * (4 * H_) + colbase + 2 * cp;
        ui = *(const unsigned int*)(gxp + 0 * H_);
        uf = *(const unsigned int*)(gxp + 1 * H_);
        ug = *(const unsigned int*)(gxp + 2 * H_);
        uo = *(const unsigned int*)(gxp + 3 * H_);
      }

      // h_t read: sc0 sc1 bypasses possibly-stale local caches
      const size_t toff = (size_t)t * (B_ * H_);
      short8 hx0[8], hx1[8];
#pragma unroll
      for (int i = 0; i < 8; ++i) {
        asm volatile("global_load_dwordx4 %0, %1, off sc0 sc1"
                     : "=v"(hx0[i]) : "v"(hb0 + toff + i * 32) : "memory");
        asm volatile("global_load_dwordx4 %0, %1, off sc0 sc1"
                     : "=v"(hx1[i]) : "v"(hb1 + toff + i * 32) : "memory");
      }
      asm volatile("s_waitcnt vmcnt(0)" ::: "memory");
      __builtin_amdgcn_sched_barrier(0);   // rule#18

      // 32 MFMAs: 8 k-chunks x 2 col-frags x 2 batch-frags
      floatx4 A0 = (floatx4){0.f,0.f,0.f,0.f}, A1 = A0, B0 = A0, B1 = A0;
#pragma unroll
      for (int i = 0; i < 8; ++i) {
        short8 w0 = *(const short8*)(wb0 + i * 32);
        short8 w1 = *(const short8*)(wb1 + i * 32);
        A0 = __builtin_amdgcn_mfma_f32_16x16x32_bf16(hx0[i], w0, A0, 0, 0, 0);
        A1 = __builtin_amdgcn_mfma_f32_16x16x32_bf16(hx0[i], w1, A1, 0, 0, 0);
        B0 = __builtin_amdgcn_mfma_f32_16x16x32_bf16(hx1[i], w0, B0, 0, 0, 0);
        B1 = __builtin_amdgcn_mfma_f32_16x16x32_bf16(hx1[i], w1, B1, 0, 0, 0);
      }
#pragma unroll
      for (int r = 0; r < 4; ++r) {
        gbuf[kq][bf0 * 16 + quad * 4 + r][l15]      = A0[r];
        gbuf[kq][bf0 * 16 + quad * 4 + r][16 + l15] = A1[r];
        gbuf[kq][bf1 * 16 + quad * 4 + r][l15]      = B0[r];
        gbuf[kq][bf1 * 16 + quad * 4 + r][16 + l15] = B1[r];
      }
      __syncthreads();

      // cell math: thread owns (batch cb, cols colbase+2cp, +1)
      if (tid < 256) {
        const int c0c = 2 * cp, c1c = 2 * cp + 1;
        float giA = gbuf[0][cb][ 0 + c0c] + gbuf[1][cb][ 0 + c0c]
                  + gbuf[2][cb][ 0 + c0c] + gbuf[3][cb][ 0 + c0c] + bf2f((unsigned short)(ui & 0xffff));
        float gfA = gbuf[0][cb][ 8 + c0c] + gbuf[1][cb][ 8 + c0c]
                  + gbuf[2][cb][ 8 + c0c] + gbuf[3][cb][ 8 + c0c] + bf2f((unsigned short)(uf & 0xffff));
        float ggA = gbuf[0][cb][16 + c0c] + gbuf[1][cb][16 + c0c]
                  + gbuf[2][cb][16 + c0c] + gbuf[3][cb][16 + c0c] + bf2f((unsigned short)(ug & 0xffff));
        float goA = gbuf[0][cb][24 + c0c] + gbuf[1][cb][24 + c0c]
                  + gbuf[2][cb][24 + c0c] + gbuf[3][cb][24 + c0c] + bf2f((unsigned short)(uo & 0xffff));
        float giB = gbuf[0][cb][ 0 + c1c] + gbuf[1][cb][ 0 + c1c]
                  + gbuf[2][cb][ 0 + c1c] + gbuf[3][cb][ 0 + c1c] + bf2f((unsigned short)(ui >> 16));
        float gfB = gbuf[0][cb][ 8 + c1c] + gbuf[1][cb][ 8 + c1c]
                  + gbuf[2][cb][ 8 + c1c] + gbuf[3][cb][ 8 + c1c] + bf2f((unsigned short)(uf >> 16));
        float ggB = gbuf[0][cb][16 + c1c] + gbuf[1][cb][16 + c1c]
                  + gbuf[2][cb][16 + c1c] + gbuf[3][cb][16 + c1c] + bf2f((unsigned short)(ug >> 16));
        float goB = gbuf[0][cb][24 + c1c] + gbuf[1][cb][24 + c1c]
                  + gbuf[2][cb][24 + c1c] + gbuf[3][cb][24 + c1c] + bf2f((unsigned short)(uo >> 16));
        giA = sigmoidf_(giA); gfA = sigmoidf_(gfA); ggA = tanhf(ggA); goA = sigmoidf_(goA);
        giB = sigmoidf_(giB); gfB = sigmoidf_(gfB); ggB = tanhf(ggB); goB = sigmoidf_(goB);
        cA = gfA * cA + giA * ggA;
        cB = gfB * cB + giB * ggB;
        float hA = goA * tanhf(cA);
        float hB = goB * tanhf(cB);
        unsigned int hv = (unsigned int)f2bf(hA) | ((unsigned int)f2bf(hB) << 16);
        unsigned int* hop = (unsigned int*)(h_all + (size_t)(t + 1) * (B_ * H_)
                                            + (size_t)cb * H_ + colbase + 2 * cp);
        asm volatile("global_store_dword %0, %1, off sc0 sc1"
                     :: "v"(hop), "v"(hv) : "memory");
        asm volatile("s_waitcnt vmcnt(0)" ::: "memory");   // ack at LLC
      }

      __syncthreads();                 // h stores acked; gbuf reads complete
      if (tid == 0) {                  // publish for ALL t (FC needs t=32)
        const unsigned int tg = (unsigned int)(t + 1);
        unsigned int* myf = flags + (size_t)bid * 16;
        asm volatile("global_store_dword %0, %1, off sc0 sc1"
                     :: "v"(myf), "v"(tg) : "memory");
      }
      if (t < T_ - 1 && wave == 0) {
        const unsigned int tgt = (unsigned int)(t + 1);
        for (;;) {
          unsigned int v0, v1;
          asm volatile("global_load_dword %0, %1, off sc0 sc1"
                       : "=v"(v0) : "v"(pf0) : "memory");
          asm volatile("global_load_dword %0, %1, off sc0 sc1"
                       : "=v"(v1) : "v"(pf1) : "memory");
          asm volatile("s_waitcnt vmcnt(0)" ::: "memory");
          if (__all(v0 >= tgt && v1 >= tgt)) break;
          __builtin_amdgcn_s_sleep(1);
        }
      }
      __syncthreads();                 // release into step t+1
    }
    return;
  }

  // ======================= FC role =======================
  const int f  = bid - 128;
  const int vb = f * 79;               // vocab slab [vb, vb+79)
  // one-time: stage 79 W_fc rows, XOR-swizzled (16B slot s <- chunk s^(r&7))
  for (int it = 0; it < 20; ++it) {
    int u = wave * 20 + it;            // 0..159
    if (u < 158) {
      int r = u >> 1, half = u & 1;
      int vr = vb + r; if (vr > V_ - 1) vr = V_ - 1;
      int gchunk = (half * 64 + lane) ^ (r & 7);
      gl_lds16(W_fc_b + (size_t)vr * H_ + (size_t)gchunk * 8,
               (unsigned short*)(smem + (size_t)r * 2048 + half * 1024));
    }
  }
  __syncthreads();                     // slab resident (read-only hereafter)

  for (int t = 1; t <= T_; ++t) {
    if (wave == 0) {                   // poll: all 128 step flags >= t
      const unsigned int tgt = (unsigned int)t;
      for (;;) {
        unsigned int v0, v1;
        asm volatile("global_load_dword %0, %1, off sc0 sc1"
                     : "=v"(v0) : "v"(pf0) : "memory");
        asm volatile("global_load_dword %0, %1, off sc0 sc1"
                     : "=v"(v1) : "v"(pf1) : "memory");
        asm volatile("s_waitcnt vmcnt(0)" ::: "memory");
        if (__all(v0 >= tgt && v1 >= tgt)) break;
        __builtin_amdgcn_s_sleep(1);
      }
    }
    __syncthreads();                   // h_all[t] confirmed for all waves

    if (wave >= 1 && wave <= 4) {
      const int bf = wave - 1;         // batch frag 0..3
      const unsigned short* ap =
          h_all + (size_t)t * (B_ * H_) + (size_t)(bf * 16 + l15) * H_ + quad * 8;
      float* orow = out + (size_t)(t - 1) * (B_ * V_);
      floatx4 acc[5];
#pragma unroll
      for (int c = 0; c < 5; ++c) acc[c] = (floatx4){0.f, 0.f, 0.f, 0.f};
      // per-lane LDS row bases for the 5 col-frags
      const unsigned char* lb[5];
      int sw[5];
#pragma unroll
      for (int c = 0; c < 5; ++c) {
        int lrow = c * 16 + l15;
        lb[c] = smem + (size_t)lrow * 2048;
        sw[c] = lrow & 7;
      }
#pragma unroll 4
      for (int i = 0; i < 32; ++i) {
        short8 a = *(const short8*)(ap + i * 32);   // load once, reuse x5
        const int ch = quad + i * 4;
#pragma unroll
        for (int c = 0; c < 5; ++c) {
          short8 b = *(const short8*)(lb[c] + ((ch ^ sw[c]) << 4));
          acc[c] = __builtin_amdgcn_mfma_f32_16x16x32_bf16(a, b, acc[c], 0, 0, 0);
        }
      }
#pragma unroll
      for (int c = 0; c < 5; ++c) {
        const int lcol = c * 16 + l15;
        const int col  = vb + lcol;
        if (lcol < 79 && col < V_) {
          const float bs = b_fc[col];
#pragma unroll
          for (int r = 0; r < 4; ++r)
            orow[(size_t)(bf * 16 + quad * 4 + r) * V_ + col] = sigmoidf_(acc[c][r] + bs);
        }
      }
    }
    // no bottom barrier: wave0 may race ahead to poll t+1 while waves 1-4
    // finish FC(t); the next __syncthreads joins them. LDS is read-only.
  }
}

// ---------------------------------------------------------------------------
extern "C" void kernel_launch(void* const* d_in, const int* in_sizes, int n_in,
                              void* d_out, int out_size, void* d_ws, size_t ws_size,
                              hipStream_t stream) {
  const float* features    = (const float*)d_in[0];
  const int*   captions    = (const int*)d_in[1];
  const float* embed_table = (const float*)d_in[2];
  const float* W_init_h    = (const float*)d_in[3];
  const float* b_init_h    = (const float*)d_in[4];
  const float* W_init_c    = (const float*)d_in[5];
  const float* b_init_c    = (const float*)d_in[6];
  const float* W_ih        = (const float*)d_in[7];
  const float* b_ih        = (const float*)d_in[8];
  const float* W_hh        = (const float*)d_in[9];
  const float* b_hh        = (const float*)d_in[10];
  const float* W_fc        = (const float*)d_in[11];
  const float* b_fc        = (const float*)d_in[12];
  float* out = (float*)d_out;

  // ---- workspace carve-up (bump allocator, 256B aligned) ----
  char* ws = (char*)d_ws;
  auto alloc = [&](size_t bytes) -> char* {
    char* p = ws;
    ws += (bytes + 255) & ~(size_t)255;
    return p;
  };
  unsigned short* W_ih_b  = (unsigned short*)alloc((size_t)4 * H_ * E_ * 2);
  unsigned short* W_hh_b  = (unsigned short*)alloc((size_t)4 * H_ * H_ * 2);
  unsigned short* W_fc_b  = (unsigned short*)alloc((size_t)V_ * H_ * 2);
  // NOTE: Wih0_b and Wic0_b must stay CONTIGUOUS (fused [2H,F] init GEMM).
  unsigned short* Wih0_b  = (unsigned short*)alloc((size_t)H_ * F_ * 2);
  unsigned short* Wic0_b  = (unsigned short*)alloc((size_t)H_ * F_ * 2);
  unsigned short* feat_b  = (unsigned short*)alloc((size_t)B_ * F_ * 2);
  unsigned short* emb_b   = (unsigned short*)alloc((size_t)T_ * B_ * E_ * 2);
  unsigned short* gx_b    = (unsigned short*)alloc((size_t)T_ * B_ * 4 * H_ * 2);
  unsigned short* h_all   = (unsigned short*)alloc((size_t)(T_ + 1) * B_ * H_ * 2);
  float*          c_f32   = (float*)alloc((size_t)B_ * H_ * 4);
  unsigned int*   flags   = (unsigned int*)alloc((size_t)NFLAGW * 4);
  (void)ws_size; (void)in_sizes; (void)n_in; (void)out_size; (void)Wic0_b;

  // ---- one fused fp32->bf16 conversion + flag reset ----
  hipLaunchKernelGGL(cvt_all, dim3(4096), dim3(256), 0, stream,
                     W_ih, W_hh, W_fc, W_init_h, W_init_c, features,
                     W_ih_b, W_hh_b, W_fc_b, Wih0_b, Wic0_b, feat_b, flags);

  hipLaunchKernelGGL(embed_gather, dim3(T_ * B_), dim3(128), 0, stream,
                     embed_table, captions, emb_b);

  // ---- fused h0|c0 init: one GEMM over N=2048 (Wih0_b||Wic0_b contiguous) -
  hipLaunchKernelGGL((mfma_gemm128<0, 1, 1>), dim3(1, 2 * H_ / 128), dim3(256), 0, stream,
                     feat_b, Wih0_b, b_init_h, b_init_c,
                     (void*)h_all, (void*)c_f32, B_, 2 * H_, F_);

  // ---- gx = emb @ W_ih^T + b_ih + b_hh for all t ----
  hipLaunchKernelGGL((mfma_gemm128<0, 1, 0>), dim3(T_ * B_ / 128, 4 * H_ / 128), dim3(256), 0, stream,
                     emb_b, W_ih_b, b_ih, b_hh, (void*)gx_b, (void*)nullptr,
                     T_ * B_, 4 * H_, E_);

  // ---- 32 steps + entire FC in ONE role-split persistent kernel ----------
  hipLaunchKernelGGL(lstm_fused, dim3(256), dim3(512), 0, stream,
                     W_hh_b, gx_b, c_f32, h_all, flags, W_fc_b, b_fc, out);
}